// Round 7
// baseline (216.225 us; speedup 1.0000x reference)
//
#include <hip/hip_runtime.h>
#include <hip/hip_bf16.h>
#include <cstdint>
#include <cstddef>

// B=4, C=128, L=4096, H=4 (hd=32), GROUPS=32, EPS=1e-5
// gn_stats (split stats: 2 blocks/group, partial sums; + weight cvt)
// -> MFMA qkv v2 (this round): grid (L/32, B) = 512 blocks; x staged ONCE per block
//    (was 3x: grid.y=3 re-staged the same tile); all 6 output 64-row tiles looped
//    in-block. x traffic 24MB -> 8MB, GN math /3.
// -> MFMA flash attention v8 (this round): v7 structure (64-q blocks, 8 waves =
//    2 q-tiles x 4 s-stripes, fixed K swizzle) + l via ones-MFMA
//    (aL = mfma_32x32x16_f16(ones, P, aL)) replacing the 8-deep serial fdot2 chain —
//    shifts ~16cyc/iter from the saturated VALU pipe to the 24%-busy MFMA pipe and
//    removes a serial dependency.
// -> MFMA proj v2 (this round): grid (L/32, B) = 512 blocks; BOTH 64-out halves per
//    block (ot tile read once, was 2x). Ls[128][33] transpose, 1 barrier.
//
// ws layout (bytes):
//   wq_b  bf16 49,152   @ 0
//   wp_b  bf16 16,384   @ 98,304
//   bp_f  f32  128      @ 131,072
//   gpart f32x2 2,048   @ 131,584   [b][g][half] (s, ss)
//   Qt    bf16 2,097,152 @ 8,388,608   [b*H+h][l][32]
//   Kt    bf16 2,097,152 @ 12,582,912  [b*H+h][l][32]
//   Vb    fp16 2,097,152 @ 16,777,216  [b*H+h][32][l]
//   ot    bf16 2,097,152 @ 20,971,520  [b][l][128]

#define B_ 4
#define C_ 128
#define L_ 4096
#define H_ 4
#define HD_ 32
#define NG_ 32
#define CPG_ 4
#define EPS_ 1e-5f
#define QKSCALE_ 0.5050097650430367f  // 32^(-1/4) * sqrt(log2 e)

typedef __attribute__((ext_vector_type(8))) short bf16x8;
typedef __attribute__((ext_vector_type(8))) unsigned short u16x8;
typedef __attribute__((ext_vector_type(4))) float f32x4;
typedef __attribute__((ext_vector_type(16))) float f32x16;
typedef __attribute__((ext_vector_type(2))) _Float16 f16x2;
typedef __attribute__((ext_vector_type(4))) _Float16 f16x4;
typedef __attribute__((ext_vector_type(8))) _Float16 f16x8;
typedef __attribute__((ext_vector_type(2))) unsigned int u32x2;
typedef __attribute__((ext_vector_type(4))) unsigned int u32x4;

#if __has_builtin(__builtin_amdgcn_exp2f)
#define EXP2F(x) __builtin_amdgcn_exp2f(x)
#else
#define EXP2F(x) exp2f(x)
#endif

__device__ __forceinline__ float bu2f(unsigned short u) {
  return __builtin_bit_cast(float, (unsigned int)(((unsigned int)u) << 16));
}
__device__ __forceinline__ unsigned short f2bu(float f) {
  unsigned int u = __builtin_bit_cast(unsigned int, f);
  unsigned int r = (u + 0x7fffu + ((u >> 16) & 1u)) >> 16;  // RNE
  return (unsigned short)r;
}
__device__ __forceinline__ float4 u42f4(ushort4 u) {
  return make_float4(bu2f(u.x), bu2f(u.y), bu2f(u.z), bu2f(u.w));
}
__device__ __forceinline__ unsigned int pkbf(float a, float b) {
  return (unsigned int)f2bu(a) | ((unsigned int)f2bu(b) << 16);
}
__device__ __forceinline__ f16x2 pkhf2(float a, float b) {
#if __has_builtin(__builtin_amdgcn_cvt_pkrtz)
  return __builtin_bit_cast(f16x2, __builtin_amdgcn_cvt_pkrtz(a, b));
#else
  f16x2 r;
  r[0] = (_Float16)a;
  r[1] = (_Float16)b;
  return r;
#endif
}
__device__ __forceinline__ unsigned int pkhf(float a, float b) {
  return __builtin_bit_cast(unsigned int, pkhf2(a, b));
}

// async global->LDS DMA, 16B per lane. LDS dest must be wave-uniform base + lane*16.
__device__ __forceinline__ void gload16(const void* g, void* l) {
  __builtin_amdgcn_global_load_lds(
      (const __attribute__((address_space(1))) unsigned int*)g,
      (__attribute__((address_space(3))) unsigned int*)l, 16, 0, 0);
}

// fp32-vs-bf16 detection via wave-0 ballot — proven R9.
__device__ __forceinline__ bool detect_fast(const ushort* x) {
  __shared__ int flag_s;
  int t = threadIdx.x;
  if (t < 64) {
    int e = (x[t] >> 7) & 0xFF;
    unsigned long long m = __ballot((e < 64) || (e > 192));
    if (t == 0) flag_s = (__popcll(m) > 4) ? 1 : 0;
  }
  __syncthreads();
  return flag_s != 0;
}

__device__ __forceinline__ float4 ldx4(const void* x, size_t idx, bool f32) {
  if (f32) return *((const float4*)x + (idx >> 2));
  ushort4 u = *((const ushort4*)x + (idx >> 2));
  return u42f4(u);
}

// ---------------------------------------------------------------- GN stats + weight cvt
// Stats split: 2 blocks per (b,g), each reduces a 2048-L half of all 4 channels and
// stores a raw partial (s, ss) — no atomics, finalized inside qkv.
__global__ __launch_bounds__(256) void gn_stats(const void* __restrict__ x,
                                                const void* __restrict__ wq,
                                                const void* __restrict__ wp,
                                                const void* __restrict__ bp,
                                                ushort* __restrict__ wq_b,
                                                ushort* __restrict__ wp_b,
                                                float* __restrict__ bp_f,
                                                float2* __restrict__ gpart) {
  bool f32 = detect_fast((const ushort*)x);
  int blk = blockIdx.x;
  int t = threadIdx.x;

  if (blk >= 256) {
    int i0 = ((blk - 256) * 256 + t) * 8;
#pragma unroll
    for (int k = 0; k < 8; ++k) {
      int i = i0 + k;
      if (i >= 65664) break;
      if (i < 49152) {
        wq_b[i] = f32 ? f2bu(((const float*)wq)[i]) : ((const ushort*)wq)[i];
      } else if (i < 65536) {
        int off = i - 49152;
        wp_b[off] = f32 ? f2bu(((const float*)wp)[off]) : ((const ushort*)wp)[off];
      } else {
        int off = i - 65536;
        bp_f[off] = f32 ? ((const float*)bp)[off] : bu2f(((const ushort*)bp)[off]);
      }
    }
    return;
  }

  int b = blk >> 6, rem = blk & 63;
  int g = rem >> 1, half = rem & 1;
  size_t base = ((size_t)b * C_ + (size_t)g * CPG_) * L_ + (size_t)half * 2048;

  float s = 0.f, ss = 0.f;
#pragma unroll
  for (int cc = 0; cc < 4; ++cc) {
#pragma unroll
    for (int i = 0; i < 2; ++i) {
      size_t e = base + (size_t)cc * L_ + i * 1024 + t * 4;
      float4 f = ldx4(x, e, f32);
      s += f.x + f.y + f.z + f.w;
      ss += f.x * f.x + f.y * f.y + f.z * f.z + f.w * f.w;
    }
  }
#pragma unroll
  for (int m = 32; m >= 1; m >>= 1) {
    s += __shfl_xor(s, m, 64);
    ss += __shfl_xor(ss, m, 64);
  }
  __shared__ float red[4][2];
  int wv = t >> 6;
  if ((t & 63) == 0) { red[wv][0] = s; red[wv][1] = ss; }
  __syncthreads();
  if (t == 0) {
    float ts = red[0][0] + red[1][0] + red[2][0] + red[3][0];
    float tss = red[0][1] + red[1][1] + red[2][1] + red[3][1];
    gpart[(b * 32 + g) * 2 + half] = make_float2(ts, tss);
  }
}

// ---------------------------------------------------------------- QKV GEMM v2
// Grid (L/32, B). Stage 32-L x-tile (GN inline) ONCE; loop all 6 output 64-row tiles.
__global__ __launch_bounds__(256) void qkv_kernel(const ushort* __restrict__ wq_b,
                                                  const void* __restrict__ x,
                                                  const float2* __restrict__ gpart,
                                                  const void* __restrict__ gm,
                                                  const void* __restrict__ bt,
                                                  ushort* __restrict__ Qt,
                                                  ushort* __restrict__ Kt,
                                                  ushort* __restrict__ Vb) {
  bool f32 = detect_fast((const ushort*)x);
  __shared__ alignas(16) ushort Hs[32][136];
  __shared__ alignas(16) float Ls[32][69];
  __shared__ float2 abs_s[128];

  int lx = blockIdx.x, b = blockIdx.y;
  int t = threadIdx.x;
  int w = t >> 6, lane = t & 63, l16 = lane & 15, q = lane >> 4, q8 = q * 8;

  if (t < 64) {
#pragma unroll
    for (int k = 0; k < 2; ++k) {
      int c = 2 * t + k;
      int g = c >> 2;
      float2 p0 = gpart[(b * 32 + g) * 2];
      float2 p1 = gpart[(b * 32 + g) * 2 + 1];
      float mu = (p0.x + p1.x) * (1.0f / 16384.0f);
      float var = (p0.y + p1.y) * (1.0f / 16384.0f) - mu * mu;
      float rs = rsqrtf(var + EPS_);
      float ga = f32 ? ((const float*)gm)[c] : bu2f(((const ushort*)gm)[c]);
      float be = f32 ? ((const float*)bt)[c] : bu2f(((const ushort*)bt)[c]);
      abs_s[c] = make_float2(ga * rs, be - mu * ga * rs);
    }
  }
  __syncthreads();

  {
    int u = t & 63, lh = w * 8;
    int c0 = 2 * u;
    float2 ab0 = abs_s[c0];
    float2 ab1 = abs_s[c0 + 1];
    size_t xo = ((size_t)b * C_ + c0) * L_ + (size_t)lx * 32 + lh;
#pragma unroll
    for (int j = 0; j < 2; ++j) {
      float4 f0 = ldx4(x, xo + j * 4, f32);
      float4 f1 = ldx4(x, xo + L_ + j * 4, f32);
      float n0[4] = {f0.x * ab0.x + ab0.y, f0.y * ab0.x + ab0.y,
                     f0.z * ab0.x + ab0.y, f0.w * ab0.x + ab0.y};
      float n1[4] = {f1.x * ab1.x + ab1.y, f1.y * ab1.x + ab1.y,
                     f1.z * ab1.x + ab1.y, f1.w * ab1.x + ab1.y};
#pragma unroll
      for (int k = 0; k < 4; ++k)
        *(unsigned int*)&Hs[lh + j * 4 + k][c0] = pkbf(n0[k], n1[k]);
    }
  }
  __syncthreads();

  for (int oy = 0; oy < 6; ++oy) {
    const ushort* wg = wq_b + (size_t)(oy * 64 + w * 16 + l16) * C_;

    f32x4 acc[2] = {{0.f, 0.f, 0.f, 0.f}, {0.f, 0.f, 0.f, 0.f}};
#pragma unroll
    for (int kc = 0; kc < 4; ++kc) {
      bf16x8 aw = *(const bf16x8*)(wg + kc * 32 + q8);
#pragma unroll
      for (int nb = 0; nb < 2; ++nb) {
        bf16x8 bh = *(const bf16x8*)&Hs[nb * 16 + l16][kc * 32 + q8];
        acc[nb] = __builtin_amdgcn_mfma_f32_16x16x32_bf16(aw, bh, acc[nb], 0, 0, 0);
      }
    }
    __syncthreads();
#pragma unroll
    for (int nb = 0; nb < 2; ++nb)
#pragma unroll
      for (int r = 0; r < 4; ++r)
        Ls[nb * 16 + l16][w * 16 + 4 * q + r] = acc[nb][r];
    __syncthreads();

#pragma unroll
    for (int hhalf = 0; hhalf < 2; ++hhalf) {
      int hh = oy * 2 + hhalf;
      int type = hh % 3, head = hh / 3;
      size_t bh = (size_t)b * H_ + head;
      if (type == 2) {
        int c_loc = t >> 3, l4 = (t & 7) * 4;
        float v[4];
#pragma unroll
        for (int jj = 0; jj < 4; ++jj) v[jj] = Ls[l4 + jj][hhalf * 32 + c_loc];
        uint2 u;
        u.x = pkhf(v[0], v[1]);
        u.y = pkhf(v[2], v[3]);
        *(uint2*)(Vb + (bh * 32 + c_loc) * L_ + (size_t)lx * 32 + l4) = u;
      } else {
        ushort* dst = type ? Kt : Qt;
        int l = t >> 3, seg = (t & 7) * 4;
        const float* src = &Ls[l][hhalf * 32 + seg];
        uint2 u;
        u.x = pkbf(src[0] * QKSCALE_, src[1] * QKSCALE_);
        u.y = pkbf(src[2] * QKSCALE_, src[3] * QKSCALE_);
        *(uint2*)(dst + ((bh * L_) + lx * 32 + l) * 32 + seg) = u;
      }
    }
  }
}

// ---------------------------------------------------------------- MFMA flash attention v8
// v7 structure; l now via ones-MFMA on the MFMA pipe (replaces 8 serial fdot2).
__global__ __launch_bounds__(512, 8) void attn_kernel(const ushort* __restrict__ Qt,
                                                      const ushort* __restrict__ Kt,
                                                      const ushort* __restrict__ Vb,
                                                      ushort* __restrict__ ot) {
  // K bufs: [0,8192),[8192,16384) ; V bufs: [16384,24576),[24576,32768)
  // epilogue overlay: Osh [8][32][33] f32 = 33792B @0 ; Lp [4][64] f32 @33792 (1024B)
  __shared__ alignas(16) char smem[35840];

  int t = threadIdx.x;
  int w = t >> 6, lane = t & 63, l31 = lane & 31, hi = lane >> 5;
  int qt = w & 1, sh = w >> 1;
  int tq0 = blockIdx.x * 64;
  int bh = blockIdx.y;
  int b = bh >> 2, head = bh & 3;
  const ushort* Qg = Qt + ((size_t)bh * L_ + tq0) * 32;
  const ushort* Kg = Kt + (size_t)bh * L_ * 32;
  const ushort* Vg = Vb + (size_t)bh * 32 * L_;

  // staging sources (pre-swizzled so linear DMA dest yields swizzled LDS)
  int rd = t >> 2, pd = t & 3;
  int kcsem = (pd - (rd >> 1)) & 3;
  const ushort* ksrc = Kg + (size_t)rd * 32 + kcsem * 8;
  int vr = t >> 4, vp = t & 15;
  int vcsem = (vp & 8) | ((vp & 7) ^ (vr & 7));
  const ushort* vsrc = Vg + (size_t)vr * L_ + vcsem * 8;

  char* kb0 = smem;
  char* kb1 = smem + 8192;
  char* vb0 = smem + 16384;
  char* vb1 = smem + 24576;

  // Q fragments (B operand): lane holds Q[q=qt*32+l31][k = 8*hi + j] (+16 for 2nd K-half)
  const ushort* qbase = Qg + (size_t)(qt * 32 + l31) * 32;
  bf16x8 qB0 = *(const bf16x8*)(qbase + 8 * hi);
  bf16x8 qB1 = *(const bf16x8*)(qbase + 16 + 8 * hi);

  f16x8 ones8;
#pragma unroll
  for (int i = 0; i < 8; ++i) ones8[i] = (_Float16)1.0f;
  const f32x16 zz = {0.f};

  // prologue: DMA tile 0 into buf A
  gload16(ksrc, kb0 + (size_t)t * 16);
  gload16(vsrc, vb0 + (size_t)t * 16);
  ksrc += 4096;
  vsrc += 128;
  __syncthreads();

  f32x16 aO = {0.f};
  f32x16 aL = {0.f};
  int s0 = 32 * sh;
  int rot = (l31 >> 1) & 3;

  int flip = 0;
  for (int it = 0; it < 32; ++it) {
    if (it < 31) {
      gload16(ksrc, (flip ? kb0 : kb1) + (size_t)t * 16);
      gload16(vsrc, (flip ? vb0 : vb1) + (size_t)t * 16);
      ksrc += 4096;
      vsrc += 128;
    }
    const ushort* kc = (const ushort*)(flip ? kb1 : kb0);
    const ushort* vc = (const ushort*)(flip ? vb1 : vb0);

    const ushort* krow = kc + (size_t)(s0 + l31) * 32;
    bf16x8 aK0 = *(const bf16x8*)(krow + ((hi + rot) & 3) * 8);
    bf16x8 aK1 = *(const bf16x8*)(krow + ((2 + hi + rot) & 3) * 8);
    f32x16 sf;
    __builtin_amdgcn_s_setprio(1);
    sf = __builtin_amdgcn_mfma_f32_32x32x16_bf16(aK0, qB0, zz, 0, 0, 0);
    sf = __builtin_amdgcn_mfma_f32_32x32x16_bf16(aK1, qB1, sf, 0, 0, 0);
    __builtin_amdgcn_s_setprio(0);

#pragma unroll
    for (int sb = 0; sb < 2; ++sb) {
      int sblk = 2 * sh + sb;
      // V fragment (A operand): V[c=l31][s = sblk*16 + 8*hi + j]
      int kci = 2 * sblk + hi;
      int vpos = (kci & 8) | ((kci & 7) ^ (l31 & 7));
      f16x8 vf = *(const f16x8*)(vc + (size_t)l31 * 128 + vpos * 8);

      float p0 = EXP2F(sf[8 * sb + 0]);
      float p1 = EXP2F(sf[8 * sb + 1]);
      float p2 = EXP2F(sf[8 * sb + 2]);
      float p3 = EXP2F(sf[8 * sb + 3]);
      float p4 = EXP2F(sf[8 * sb + 4]);
      float p5 = EXP2F(sf[8 * sb + 5]);
      float p6 = EXP2F(sf[8 * sb + 6]);
      float p7 = EXP2F(sf[8 * sb + 7]);
      f16x2 cA0 = pkhf2(p0, p1), cA1 = pkhf2(p2, p3);
      f16x2 cB0 = pkhf2(p4, p5), cB1 = pkhf2(p6, p7);

      // B-fragment repack: (w0,w2) = swap(cA0, cB0); (w1,w3) = swap(cA1, cB1)
      u32x2 r0 = __builtin_amdgcn_permlane32_swap(
          __builtin_bit_cast(unsigned int, cA0),
          __builtin_bit_cast(unsigned int, cB0), false, false);
      u32x2 r1 = __builtin_amdgcn_permlane32_swap(
          __builtin_bit_cast(unsigned int, cA1),
          __builtin_bit_cast(unsigned int, cB1), false, false);
      u32x4 pw = {r0.x, r1.x, r0.y, r1.y};
      f16x8 pf = __builtin_bit_cast(f16x8, pw);

      __builtin_amdgcn_s_setprio(1);
      aO = __builtin_amdgcn_mfma_f32_32x32x16_f16(vf, pf, aO, 0, 0, 0);
      aL = __builtin_amdgcn_mfma_f32_32x32x16_f16(ones8, pf, aL, 0, 0, 0);
      __builtin_amdgcn_s_setprio(0);
    }
    __syncthreads();
    flip ^= 1;
  }

  // ---- epilogue: write partials (padded rows: bank = (l31 + word) % 32, conflict-free)
  float* Osh = (float*)smem;                // [slot=sh*2+qt][q=32][c=33pad]
  float* Lp = (float*)(smem + 33792);       // [sh][64] (aL rows identical; hi0 writes)
  {
    float* ob = Osh + (size_t)(sh * 2 + qt) * (32 * 33) + (size_t)l31 * 33;
#pragma unroll
    for (int reg = 0; reg < 16; ++reg) {
      int R = (reg & 3) + 8 * (reg >> 2) + 4 * hi;
      ob[R] = aO[reg];
    }
    if (hi == 0) Lp[sh * 64 + qt * 32 + l31] = aL[0];
  }
  __syncthreads();

  // combine 4 s-stripes, normalize, pack bf16, store
  {
    int qloc = t >> 3, seg = (t & 7) * 4;
    int qt2 = qloc >> 5, q31 = qloc & 31;
    float lt = Lp[qloc] + Lp[64 + qloc] + Lp[128 + qloc] + Lp[192 + qloc];
    float inv = 1.0f / lt;
    float o[4] = {0.f, 0.f, 0.f, 0.f};
#pragma unroll
    for (int s = 0; s < 4; ++s) {
      const float* op = Osh + (size_t)(s * 2 + qt2) * (32 * 33) + (size_t)q31 * 33 + seg;
#pragma unroll
      for (int jj = 0; jj < 4; ++jj) o[jj] += op[jj];
    }
    uint2 u;
    u.x = pkbf(o[0] * inv, o[1] * inv);
    u.y = pkbf(o[2] * inv, o[3] * inv);
    *(uint2*)(ot + ((size_t)b * L_ + tq0 + qloc) * C_ + head * 32 + seg) = u;
  }
}

// ---------------------------------------------------------------- Proj v2 + bias + residual
// Grid (L/32, B): both 64-out halves per block — ot tile read once.
__global__ __launch_bounds__(256) void proj_kernel(const ushort* __restrict__ wp_b,
                                                   const float* __restrict__ bias,
                                                   const void* __restrict__ x,
                                                   const ushort* __restrict__ ot,
                                                   void* __restrict__ out) {
  bool f32 = detect_fast((const ushort*)x);
  __shared__ alignas(16) float Ls[128][33];

  int lx = blockIdx.x, b = blockIdx.y;
  int t = threadIdx.x;
  int w = t >> 6, lane = t & 63, l16 = lane & 15, q = lane >> 4, q8 = q * 8;

  const ushort* wg0 = wp_b + (size_t)(w * 16 + l16) * C_;
  const ushort* wg1 = wp_b + (size_t)(64 + w * 16 + l16) * C_;
  const ushort* og = ot + ((size_t)b * L_ + (size_t)lx * 32) * C_;

  f32x4 acc[2][2] = {{{0.f, 0.f, 0.f, 0.f}, {0.f, 0.f, 0.f, 0.f}},
                     {{0.f, 0.f, 0.f, 0.f}, {0.f, 0.f, 0.f, 0.f}}};
#pragma unroll
  for (int kc = 0; kc < 4; ++kc) {
    bf16x8 aw0 = *(const bf16x8*)(wg0 + kc * 32 + q8);
    bf16x8 aw1 = *(const bf16x8*)(wg1 + kc * 32 + q8);
#pragma unroll
    for (int nb = 0; nb < 2; ++nb) {
      bf16x8 bo = *(const bf16x8*)(og + (size_t)(nb * 16 + l16) * C_ + kc * 32 + q8);
      acc[0][nb] = __builtin_amdgcn_mfma_f32_16x16x32_bf16(aw0, bo, acc[0][nb], 0, 0, 0);
      acc[1][nb] = __builtin_amdgcn_mfma_f32_16x16x32_bf16(aw1, bo, acc[1][nb], 0, 0, 0);
    }
  }
#pragma unroll
  for (int oy = 0; oy < 2; ++oy)
#pragma unroll
    for (int nb = 0; nb < 2; ++nb)
#pragma unroll
      for (int r = 0; r < 4; ++r)
        Ls[oy * 64 + w * 16 + 4 * q + r][nb * 16 + l16] = acc[oy][nb][r];
  __syncthreads();

  {
    int o_loc = t >> 1, ls0 = (t & 1) * 16;
    float bv = bias[o_loc];
    size_t off = ((size_t)b * C_ + o_loc) * L_ + (size_t)lx * 32 + ls0;
#pragma unroll
    for (int jj = 0; jj < 4; ++jj) {
      float4 xf = ldx4(x, off + jj * 4, f32);
      const float* sp = &Ls[o_loc][ls0 + jj * 4];
      float4 r = make_float4(sp[0] + bv + xf.x, sp[1] + bv + xf.y,
                             sp[2] + bv + xf.z, sp[3] + bv + xf.w);
      if (f32) {
        *(float4*)((float*)out + off + jj * 4) = r;
      } else {
        *(ushort4*)((ushort*)out + off + jj * 4) =
            make_ushort4(f2bu(r.x), f2bu(r.y), f2bu(r.z), f2bu(r.w));
      }
    }
  }
}

// ---------------------------------------------------------------- launch
extern "C" void kernel_launch(void* const* d_in, const int* in_sizes, int n_in,
                              void* d_out, int out_size, void* d_ws, size_t ws_size,
                              hipStream_t stream) {
  const void* x      = d_in[0];
  const void* w_qkv  = d_in[1];
  const void* w_proj = d_in[2];
  const void* b_proj = d_in[3];
  const void* gamma  = d_in[4];
  const void* beta   = d_in[5];

  char* wsb = (char*)d_ws;
  ushort* wq_b  = (ushort*)(wsb + 0);
  ushort* wp_b  = (ushort*)(wsb + 98304);
  float*  bp_f  = (float*)(wsb + 131072);
  float2* gpart = (float2*)(wsb + 131584);
  ushort* Qt    = (ushort*)(wsb + 8388608);
  ushort* Kt    = (ushort*)(wsb + 12582912);
  ushort* Vb    = (ushort*)(wsb + 16777216);  // fp16
  ushort* ot    = (ushort*)(wsb + 20971520);

  gn_stats<<<dim3(289), dim3(256), 0, stream>>>(x, w_qkv, w_proj, b_proj,
                                                wq_b, wp_b, bp_f, gpart);
  qkv_kernel<<<dim3(L_ / 32, B_), dim3(256), 0, stream>>>(wq_b, x, gpart, gamma, beta,
                                                          Qt, Kt, Vb);
  attn_kernel<<<dim3(L_ / 64, B_ * H_), dim3(512), 0, stream>>>(Qt, Kt, Vb, ot);
  proj_kernel<<<dim3(L_ / 32, B_), dim3(256), 0, stream>>>(wp_b, bp_f, x, ot, d_out);
}

// Round 8
// 147.975 us; speedup vs baseline: 1.4612x; 1.4612x over previous
//
#include <hip/hip_runtime.h>
#include <hip/hip_bf16.h>
#include <cstdint>
#include <cstddef>

// B=4, C=128, L=4096, H=4 (hd=32), GROUPS=32, EPS=1e-5
// gn_stats (split stats) -> MFMA qkv v2 (x staged once, 6 out-tiles looped)
// -> MFMA flash attention v9 (this round):
//      R6 wave mapping (64-q blocks, 8 waves = 2 q-tiles x 4 s-stripes, fixed K swizzle)
//      + TWO-TILE IN-WAVE PIPELINE: QK(tile i+1) co-scheduled with softmax+PV(tile i)
//        (breaks the per-phase lockstep burst that capped every pipe at <62%).
//      + 4-slot LDS ring (64KB), vmcnt(0)-drain one iter after issue, raw s_barrier.
//      + l via ones-MFMA (register-safe now): __launch_bounds__(512,4) = 128 VGPR
//        budget — R7's 64-VGPR cap caused the spill catastrophe (FETCH 200MB).
// -> MFMA proj v2 (both out-halves per block).
//
// ws layout (bytes):
//   wq_b  bf16 49,152   @ 0
//   wp_b  bf16 16,384   @ 98,304
//   bp_f  f32  128      @ 131,072
//   gpart f32x2 2,048   @ 131,584   [b][g][half] (s, ss)
//   Qt    bf16 2,097,152 @ 8,388,608   [b*H+h][l][32]
//   Kt    bf16 2,097,152 @ 12,582,912  [b*H+h][l][32]
//   Vb    fp16 2,097,152 @ 16,777,216  [b*H+h][32][l]
//   ot    bf16 2,097,152 @ 20,971,520  [b][l][128]

#define B_ 4
#define C_ 128
#define L_ 4096
#define H_ 4
#define HD_ 32
#define NG_ 32
#define CPG_ 4
#define EPS_ 1e-5f
#define QKSCALE_ 0.5050097650430367f  // 32^(-1/4) * sqrt(log2 e)

typedef __attribute__((ext_vector_type(8))) short bf16x8;
typedef __attribute__((ext_vector_type(8))) unsigned short u16x8;
typedef __attribute__((ext_vector_type(4))) float f32x4;
typedef __attribute__((ext_vector_type(16))) float f32x16;
typedef __attribute__((ext_vector_type(2))) _Float16 f16x2;
typedef __attribute__((ext_vector_type(4))) _Float16 f16x4;
typedef __attribute__((ext_vector_type(8))) _Float16 f16x8;
typedef __attribute__((ext_vector_type(2))) unsigned int u32x2;
typedef __attribute__((ext_vector_type(4))) unsigned int u32x4;

#if __has_builtin(__builtin_amdgcn_exp2f)
#define EXP2F(x) __builtin_amdgcn_exp2f(x)
#else
#define EXP2F(x) exp2f(x)
#endif

__device__ __forceinline__ float bu2f(unsigned short u) {
  return __builtin_bit_cast(float, (unsigned int)(((unsigned int)u) << 16));
}
__device__ __forceinline__ unsigned short f2bu(float f) {
  unsigned int u = __builtin_bit_cast(unsigned int, f);
  unsigned int r = (u + 0x7fffu + ((u >> 16) & 1u)) >> 16;  // RNE
  return (unsigned short)r;
}
__device__ __forceinline__ float4 u42f4(ushort4 u) {
  return make_float4(bu2f(u.x), bu2f(u.y), bu2f(u.z), bu2f(u.w));
}
__device__ __forceinline__ unsigned int pkbf(float a, float b) {
  return (unsigned int)f2bu(a) | ((unsigned int)f2bu(b) << 16);
}
__device__ __forceinline__ f16x2 pkhf2(float a, float b) {
#if __has_builtin(__builtin_amdgcn_cvt_pkrtz)
  return __builtin_bit_cast(f16x2, __builtin_amdgcn_cvt_pkrtz(a, b));
#else
  f16x2 r;
  r[0] = (_Float16)a;
  r[1] = (_Float16)b;
  return r;
#endif
}
__device__ __forceinline__ unsigned int pkhf(float a, float b) {
  return __builtin_bit_cast(unsigned int, pkhf2(a, b));
}

// async global->LDS DMA, 16B per lane. LDS dest must be wave-uniform base + lane*16.
__device__ __forceinline__ void gload16(const void* g, void* l) {
  __builtin_amdgcn_global_load_lds(
      (const __attribute__((address_space(1))) unsigned int*)g,
      (__attribute__((address_space(3))) unsigned int*)l, 16, 0, 0);
}

// fp32-vs-bf16 detection via wave-0 ballot — proven R9.
__device__ __forceinline__ bool detect_fast(const ushort* x) {
  __shared__ int flag_s;
  int t = threadIdx.x;
  if (t < 64) {
    int e = (x[t] >> 7) & 0xFF;
    unsigned long long m = __ballot((e < 64) || (e > 192));
    if (t == 0) flag_s = (__popcll(m) > 4) ? 1 : 0;
  }
  __syncthreads();
  return flag_s != 0;
}

__device__ __forceinline__ float4 ldx4(const void* x, size_t idx, bool f32) {
  if (f32) return *((const float4*)x + (idx >> 2));
  ushort4 u = *((const ushort4*)x + (idx >> 2));
  return u42f4(u);
}

// ---------------------------------------------------------------- GN stats + weight cvt
__global__ __launch_bounds__(256) void gn_stats(const void* __restrict__ x,
                                                const void* __restrict__ wq,
                                                const void* __restrict__ wp,
                                                const void* __restrict__ bp,
                                                ushort* __restrict__ wq_b,
                                                ushort* __restrict__ wp_b,
                                                float* __restrict__ bp_f,
                                                float2* __restrict__ gpart) {
  bool f32 = detect_fast((const ushort*)x);
  int blk = blockIdx.x;
  int t = threadIdx.x;

  if (blk >= 256) {
    int i0 = ((blk - 256) * 256 + t) * 8;
#pragma unroll
    for (int k = 0; k < 8; ++k) {
      int i = i0 + k;
      if (i >= 65664) break;
      if (i < 49152) {
        wq_b[i] = f32 ? f2bu(((const float*)wq)[i]) : ((const ushort*)wq)[i];
      } else if (i < 65536) {
        int off = i - 49152;
        wp_b[off] = f32 ? f2bu(((const float*)wp)[off]) : ((const ushort*)wp)[off];
      } else {
        int off = i - 65536;
        bp_f[off] = f32 ? ((const float*)bp)[off] : bu2f(((const ushort*)bp)[off]);
      }
    }
    return;
  }

  int b = blk >> 6, rem = blk & 63;
  int g = rem >> 1, half = rem & 1;
  size_t base = ((size_t)b * C_ + (size_t)g * CPG_) * L_ + (size_t)half * 2048;

  float s = 0.f, ss = 0.f;
#pragma unroll
  for (int cc = 0; cc < 4; ++cc) {
#pragma unroll
    for (int i = 0; i < 2; ++i) {
      size_t e = base + (size_t)cc * L_ + i * 1024 + t * 4;
      float4 f = ldx4(x, e, f32);
      s += f.x + f.y + f.z + f.w;
      ss += f.x * f.x + f.y * f.y + f.z * f.z + f.w * f.w;
    }
  }
#pragma unroll
  for (int m = 32; m >= 1; m >>= 1) {
    s += __shfl_xor(s, m, 64);
    ss += __shfl_xor(ss, m, 64);
  }
  __shared__ float red[4][2];
  int wv = t >> 6;
  if ((t & 63) == 0) { red[wv][0] = s; red[wv][1] = ss; }
  __syncthreads();
  if (t == 0) {
    float ts = red[0][0] + red[1][0] + red[2][0] + red[3][0];
    float tss = red[0][1] + red[1][1] + red[2][1] + red[3][1];
    gpart[(b * 32 + g) * 2 + half] = make_float2(ts, tss);
  }
}

// ---------------------------------------------------------------- QKV GEMM v2
__global__ __launch_bounds__(256) void qkv_kernel(const ushort* __restrict__ wq_b,
                                                  const void* __restrict__ x,
                                                  const float2* __restrict__ gpart,
                                                  const void* __restrict__ gm,
                                                  const void* __restrict__ bt,
                                                  ushort* __restrict__ Qt,
                                                  ushort* __restrict__ Kt,
                                                  ushort* __restrict__ Vb) {
  bool f32 = detect_fast((const ushort*)x);
  __shared__ alignas(16) ushort Hs[32][136];
  __shared__ alignas(16) float Ls[32][69];
  __shared__ float2 abs_s[128];

  int lx = blockIdx.x, b = blockIdx.y;
  int t = threadIdx.x;
  int w = t >> 6, lane = t & 63, l16 = lane & 15, q = lane >> 4, q8 = q * 8;

  if (t < 64) {
#pragma unroll
    for (int k = 0; k < 2; ++k) {
      int c = 2 * t + k;
      int g = c >> 2;
      float2 p0 = gpart[(b * 32 + g) * 2];
      float2 p1 = gpart[(b * 32 + g) * 2 + 1];
      float mu = (p0.x + p1.x) * (1.0f / 16384.0f);
      float var = (p0.y + p1.y) * (1.0f / 16384.0f) - mu * mu;
      float rs = rsqrtf(var + EPS_);
      float ga = f32 ? ((const float*)gm)[c] : bu2f(((const ushort*)gm)[c]);
      float be = f32 ? ((const float*)bt)[c] : bu2f(((const ushort*)bt)[c]);
      abs_s[c] = make_float2(ga * rs, be - mu * ga * rs);
    }
  }
  __syncthreads();

  {
    int u = t & 63, lh = w * 8;
    int c0 = 2 * u;
    float2 ab0 = abs_s[c0];
    float2 ab1 = abs_s[c0 + 1];
    size_t xo = ((size_t)b * C_ + c0) * L_ + (size_t)lx * 32 + lh;
#pragma unroll
    for (int j = 0; j < 2; ++j) {
      float4 f0 = ldx4(x, xo + j * 4, f32);
      float4 f1 = ldx4(x, xo + L_ + j * 4, f32);
      float n0[4] = {f0.x * ab0.x + ab0.y, f0.y * ab0.x + ab0.y,
                     f0.z * ab0.x + ab0.y, f0.w * ab0.x + ab0.y};
      float n1[4] = {f1.x * ab1.x + ab1.y, f1.y * ab1.x + ab1.y,
                     f1.z * ab1.x + ab1.y, f1.w * ab1.x + ab1.y};
#pragma unroll
      for (int k = 0; k < 4; ++k)
        *(unsigned int*)&Hs[lh + j * 4 + k][c0] = pkbf(n0[k], n1[k]);
    }
  }
  __syncthreads();

  for (int oy = 0; oy < 6; ++oy) {
    const ushort* wg = wq_b + (size_t)(oy * 64 + w * 16 + l16) * C_;

    f32x4 acc[2] = {{0.f, 0.f, 0.f, 0.f}, {0.f, 0.f, 0.f, 0.f}};
#pragma unroll
    for (int kc = 0; kc < 4; ++kc) {
      bf16x8 aw = *(const bf16x8*)(wg + kc * 32 + q8);
#pragma unroll
      for (int nb = 0; nb < 2; ++nb) {
        bf16x8 bh = *(const bf16x8*)&Hs[nb * 16 + l16][kc * 32 + q8];
        acc[nb] = __builtin_amdgcn_mfma_f32_16x16x32_bf16(aw, bh, acc[nb], 0, 0, 0);
      }
    }
    __syncthreads();
#pragma unroll
    for (int nb = 0; nb < 2; ++nb)
#pragma unroll
      for (int r = 0; r < 4; ++r)
        Ls[nb * 16 + l16][w * 16 + 4 * q + r] = acc[nb][r];
    __syncthreads();

#pragma unroll
    for (int hhalf = 0; hhalf < 2; ++hhalf) {
      int hh = oy * 2 + hhalf;
      int type = hh % 3, head = hh / 3;
      size_t bh = (size_t)b * H_ + head;
      if (type == 2) {
        int c_loc = t >> 3, l4 = (t & 7) * 4;
        float v[4];
#pragma unroll
        for (int jj = 0; jj < 4; ++jj) v[jj] = Ls[l4 + jj][hhalf * 32 + c_loc];
        uint2 u;
        u.x = pkhf(v[0], v[1]);
        u.y = pkhf(v[2], v[3]);
        *(uint2*)(Vb + (bh * 32 + c_loc) * L_ + (size_t)lx * 32 + l4) = u;
      } else {
        ushort* dst = type ? Kt : Qt;
        int l = t >> 3, seg = (t & 7) * 4;
        const float* src = &Ls[l][hhalf * 32 + seg];
        uint2 u;
        u.x = pkbf(src[0] * QKSCALE_, src[1] * QKSCALE_);
        u.y = pkbf(src[2] * QKSCALE_, src[3] * QKSCALE_);
        *(uint2*)(dst + ((bh * L_) + lx * 32 + l) * 32 + seg) = u;
      }
    }
  }
}

// ---------------------------------------------------------------- MFMA flash attention v9
// Two-tile in-wave pipeline over a 4-slot LDS ring (slot j = tile j&3, 16KB each:
// K[0,8192) | V[8192,16384)). Per sub-iter: vmcnt(0) [drains the one outstanding DMA
// pair, issued a full body ago] -> s_barrier [cross-wave visibility] -> DMA(i+2) ->
// QK(i+1) [independent MFMA] interleaved by the scheduler with softmax+PV(i).
__global__ __launch_bounds__(512, 4) void attn_kernel(const ushort* __restrict__ Qt,
                                                      const ushort* __restrict__ Kt,
                                                      const ushort* __restrict__ Vb,
                                                      ushort* __restrict__ ot) {
  // 4 slots x 16KB = 65536. Epilogue overlay: Osh [8][32][33] f32 @0 (33792B);
  // Lp [4][64] f32 @33792 (1024B) — slot 3 (49152..65536) untouched by overlay.
  __shared__ alignas(16) char smem[65536];

  int t = threadIdx.x;
  int w = t >> 6, lane = t & 63, l31 = lane & 31, hi = lane >> 5;
  int qt = w & 1, sh = w >> 1;
  int tq0 = blockIdx.x * 64;
  int bh = blockIdx.y;
  int b = bh >> 2, head = bh & 3;
  const ushort* Qg = Qt + ((size_t)bh * L_ + tq0) * 32;
  const ushort* Kg = Kt + (size_t)bh * L_ * 32;
  const ushort* Vg = Vb + (size_t)bh * 32 * L_;

  // staging sources (pre-swizzled so linear DMA dest yields swizzled LDS)
  int rd = t >> 2, pd = t & 3;
  int kcsem = (pd - (rd >> 1)) & 3;
  const ushort* ksrc = Kg + (size_t)rd * 32 + kcsem * 8;
  int vr = t >> 4, vp = t & 15;
  int vcsem = (vp & 8) | ((vp & 7) ^ (vr & 7));
  const ushort* vsrc = Vg + (size_t)vr * L_ + vcsem * 8;

  // Q fragments (B operand)
  const ushort* qbase = Qg + (size_t)(qt * 32 + l31) * 32;
  bf16x8 qB0 = *(const bf16x8*)(qbase + 8 * hi);
  bf16x8 qB1 = *(const bf16x8*)(qbase + 16 + 8 * hi);

  f16x8 ones8;
#pragma unroll
  for (int i = 0; i < 8; ++i) ones8[i] = (_Float16)1.0f;
  const f32x16 zz = {0.f};

  int s0 = 32 * sh;
  int rot = (l31 >> 1) & 3;

#define DMA_TILE(slot)                                            \
  do {                                                            \
    char* base_ = smem + (slot) * 16384;                          \
    gload16(ksrc, base_ + (size_t)t * 16);                        \
    gload16(vsrc, base_ + 8192 + (size_t)t * 16);                 \
    ksrc += 4096;                                                 \
    vsrc += 128;                                                  \
  } while (0)

#define QK_TILE(slot, sfdst)                                                         \
  do {                                                                               \
    const ushort* kc_ = (const ushort*)(smem + (slot) * 16384);                      \
    const ushort* krow_ = kc_ + (size_t)(s0 + l31) * 32;                             \
    bf16x8 aK0_ = *(const bf16x8*)(krow_ + ((hi + rot) & 3) * 8);                    \
    bf16x8 aK1_ = *(const bf16x8*)(krow_ + ((2 + hi + rot) & 3) * 8);                \
    __builtin_amdgcn_s_setprio(1);                                                   \
    sfdst = __builtin_amdgcn_mfma_f32_32x32x16_bf16(aK0_, qB0, zz, 0, 0, 0);         \
    sfdst = __builtin_amdgcn_mfma_f32_32x32x16_bf16(aK1_, qB1, sfdst, 0, 0, 0);      \
    __builtin_amdgcn_s_setprio(0);                                                   \
  } while (0)

#define SMPV_TILE(slot, sfv)                                                         \
  do {                                                                               \
    const ushort* vc_ = (const ushort*)(smem + (slot) * 16384 + 8192);               \
    _Pragma("unroll") for (int sb = 0; sb < 2; ++sb) {                               \
      int sblk_ = 2 * sh + sb;                                                       \
      int kci_ = 2 * sblk_ + hi;                                                     \
      int vpos_ = (kci_ & 8) | ((kci_ & 7) ^ (l31 & 7));                             \
      f16x8 vf_ = *(const f16x8*)(vc_ + (size_t)l31 * 128 + vpos_ * 8);              \
      float p0_ = EXP2F(sfv[8 * sb + 0]);                                            \
      float p1_ = EXP2F(sfv[8 * sb + 1]);                                            \
      float p2_ = EXP2F(sfv[8 * sb + 2]);                                            \
      float p3_ = EXP2F(sfv[8 * sb + 3]);                                            \
      float p4_ = EXP2F(sfv[8 * sb + 4]);                                            \
      float p5_ = EXP2F(sfv[8 * sb + 5]);                                            \
      float p6_ = EXP2F(sfv[8 * sb + 6]);                                            \
      float p7_ = EXP2F(sfv[8 * sb + 7]);                                            \
      f16x2 cA0_ = pkhf2(p0_, p1_), cA1_ = pkhf2(p2_, p3_);                          \
      f16x2 cB0_ = pkhf2(p4_, p5_), cB1_ = pkhf2(p6_, p7_);                          \
      u32x2 r0_ = __builtin_amdgcn_permlane32_swap(                                  \
          __builtin_bit_cast(unsigned int, cA0_),                                    \
          __builtin_bit_cast(unsigned int, cB0_), false, false);                     \
      u32x2 r1_ = __builtin_amdgcn_permlane32_swap(                                  \
          __builtin_bit_cast(unsigned int, cA1_),                                    \
          __builtin_bit_cast(unsigned int, cB1_), false, false);                     \
      u32x4 pw_ = {r0_.x, r1_.x, r0_.y, r1_.y};                                      \
      f16x8 pf_ = __builtin_bit_cast(f16x8, pw_);                                    \
      __builtin_amdgcn_s_setprio(1);                                                 \
      aO = __builtin_amdgcn_mfma_f32_32x32x16_f16(vf_, pf_, aO, 0, 0, 0);            \
      aL = __builtin_amdgcn_mfma_f32_32x32x16_f16(ones8, pf_, aL, 0, 0, 0);          \
      __builtin_amdgcn_s_setprio(0);                                                 \
    }                                                                                \
  } while (0)

#define SYNC_RING()                                   \
  do {                                                \
    asm volatile("s_waitcnt vmcnt(0)" ::: "memory");  \
    __builtin_amdgcn_sched_barrier(0);                \
    __builtin_amdgcn_s_barrier();                     \
    __builtin_amdgcn_sched_barrier(0);                \
  } while (0)

  f32x16 aO = {0.f};
  f32x16 aL = {0.f};
  f32x16 sfA, sfB;

  // prologue: DMA tiles 0,1; wait tile 0 (allow tile-1 pair outstanding); QK(0)
  DMA_TILE(0);
  DMA_TILE(1);
  asm volatile("s_waitcnt vmcnt(2)" ::: "memory");
  __builtin_amdgcn_sched_barrier(0);
  __builtin_amdgcn_s_barrier();
  __builtin_amdgcn_sched_barrier(0);
  QK_TILE(0, sfA);

  for (int it = 0; it < 32; it += 2) {
    // even sub-iter: cur = it (sfA), next = it+1 -> sfB
    SYNC_RING();
    if (it + 2 < 32) DMA_TILE((it + 2) & 3);
    QK_TILE((it + 1) & 3, sfB);
    SMPV_TILE(it & 3, sfA);
    // odd sub-iter: cur = it+1 (sfB), next = it+2 -> sfA
    SYNC_RING();
    if (it + 3 < 32) DMA_TILE((it + 3) & 3);
    if (it + 2 < 32) QK_TILE((it + 2) & 3, sfA);
    SMPV_TILE((it + 1) & 3, sfB);
  }
  __syncthreads();

  // ---- epilogue: write partials (padded rows: bank = (l31 + word) % 32)
  float* Osh = (float*)smem;                // [slot=sh*2+qt][q=32][c=33pad]
  float* Lp = (float*)(smem + 33792);       // [sh][64] (aL rows identical; hi0 writes)
  {
    float* ob = Osh + (size_t)(sh * 2 + qt) * (32 * 33) + (size_t)l31 * 33;
#pragma unroll
    for (int reg = 0; reg < 16; ++reg) {
      int R = (reg & 3) + 8 * (reg >> 2) + 4 * hi;
      ob[R] = aO[reg];
    }
    if (hi == 0) Lp[sh * 64 + qt * 32 + l31] = aL[0];
  }
  __syncthreads();

  // combine 4 s-stripes, normalize, pack bf16, store
  {
    int qloc = t >> 3, seg = (t & 7) * 4;
    int qt2 = qloc >> 5, q31 = qloc & 31;
    float lt = Lp[qloc] + Lp[64 + qloc] + Lp[128 + qloc] + Lp[192 + qloc];
    float inv = 1.0f / lt;
    float o[4] = {0.f, 0.f, 0.f, 0.f};
#pragma unroll
    for (int s = 0; s < 4; ++s) {
      const float* op = Osh + (size_t)(s * 2 + qt2) * (32 * 33) + (size_t)q31 * 33 + seg;
#pragma unroll
      for (int jj = 0; jj < 4; ++jj) o[jj] += op[jj];
    }
    uint2 u;
    u.x = pkbf(o[0] * inv, o[1] * inv);
    u.y = pkbf(o[2] * inv, o[3] * inv);
    *(uint2*)(ot + ((size_t)b * L_ + tq0 + qloc) * C_ + head * 32 + seg) = u;
  }
#undef DMA_TILE
#undef QK_TILE
#undef SMPV_TILE
#undef SYNC_RING
}

// ---------------------------------------------------------------- Proj v2 + bias + residual
__global__ __launch_bounds__(256) void proj_kernel(const ushort* __restrict__ wp_b,
                                                   const float* __restrict__ bias,
                                                   const void* __restrict__ x,
                                                   const ushort* __restrict__ ot,
                                                   void* __restrict__ out) {
  bool f32 = detect_fast((const ushort*)x);
  __shared__ alignas(16) float Ls[128][33];

  int lx = blockIdx.x, b = blockIdx.y;
  int t = threadIdx.x;
  int w = t >> 6, lane = t & 63, l16 = lane & 15, q = lane >> 4, q8 = q * 8;

  const ushort* wg0 = wp_b + (size_t)(w * 16 + l16) * C_;
  const ushort* wg1 = wp_b + (size_t)(64 + w * 16 + l16) * C_;
  const ushort* og = ot + ((size_t)b * L_ + (size_t)lx * 32) * C_;

  f32x4 acc[2][2] = {{{0.f, 0.f, 0.f, 0.f}, {0.f, 0.f, 0.f, 0.f}},
                     {{0.f, 0.f, 0.f, 0.f}, {0.f, 0.f, 0.f, 0.f}}};
#pragma unroll
  for (int kc = 0; kc < 4; ++kc) {
    bf16x8 aw0 = *(const bf16x8*)(wg0 + kc * 32 + q8);
    bf16x8 aw1 = *(const bf16x8*)(wg1 + kc * 32 + q8);
#pragma unroll
    for (int nb = 0; nb < 2; ++nb) {
      bf16x8 bo = *(const bf16x8*)(og + (size_t)(nb * 16 + l16) * C_ + kc * 32 + q8);
      acc[0][nb] = __builtin_amdgcn_mfma_f32_16x16x32_bf16(aw0, bo, acc[0][nb], 0, 0, 0);
      acc[1][nb] = __builtin_amdgcn_mfma_f32_16x16x32_bf16(aw1, bo, acc[1][nb], 0, 0, 0);
    }
  }
#pragma unroll
  for (int oy = 0; oy < 2; ++oy)
#pragma unroll
    for (int nb = 0; nb < 2; ++nb)
#pragma unroll
      for (int r = 0; r < 4; ++r)
        Ls[oy * 64 + w * 16 + 4 * q + r][nb * 16 + l16] = acc[oy][nb][r];
  __syncthreads();

  {
    int o_loc = t >> 1, ls0 = (t & 1) * 16;
    float bv = bias[o_loc];
    size_t off = ((size_t)b * C_ + o_loc) * L_ + (size_t)lx * 32 + ls0;
#pragma unroll
    for (int jj = 0; jj < 4; ++jj) {
      float4 xf = ldx4(x, off + jj * 4, f32);
      const float* sp = &Ls[o_loc][ls0 + jj * 4];
      float4 r = make_float4(sp[0] + bv + xf.x, sp[1] + bv + xf.y,
                             sp[2] + bv + xf.z, sp[3] + bv + xf.w);
      if (f32) {
        *(float4*)((float*)out + off + jj * 4) = r;
      } else {
        *(ushort4*)((ushort*)out + off + jj * 4) =
            make_ushort4(f2bu(r.x), f2bu(r.y), f2bu(r.z), f2bu(r.w));
      }
    }
  }
}

// ---------------------------------------------------------------- launch
extern "C" void kernel_launch(void* const* d_in, const int* in_sizes, int n_in,
                              void* d_out, int out_size, void* d_ws, size_t ws_size,
                              hipStream_t stream) {
  const void* x      = d_in[0];
  const void* w_qkv  = d_in[1];
  const void* w_proj = d_in[2];
  const void* b_proj = d_in[3];
  const void* gamma  = d_in[4];
  const void* beta   = d_in[5];

  char* wsb = (char*)d_ws;
  ushort* wq_b  = (ushort*)(wsb + 0);
  ushort* wp_b  = (ushort*)(wsb + 98304);
  float*  bp_f  = (float*)(wsb + 131072);
  float2* gpart = (float2*)(wsb + 131584);
  ushort* Qt    = (ushort*)(wsb + 8388608);
  ushort* Kt    = (ushort*)(wsb + 12582912);
  ushort* Vb    = (ushort*)(wsb + 16777216);  // fp16
  ushort* ot    = (ushort*)(wsb + 20971520);

  gn_stats<<<dim3(289), dim3(256), 0, stream>>>(x, w_qkv, w_proj, b_proj,
                                                wq_b, wp_b, bp_f, gpart);
  qkv_kernel<<<dim3(L_ / 32, B_), dim3(256), 0, stream>>>(wq_b, x, gpart, gamma, beta,
                                                          Qt, Kt, Vb);
  attn_kernel<<<dim3(L_ / 64, B_ * H_), dim3(512), 0, stream>>>(Qt, Kt, Vb, ot);
  proj_kernel<<<dim3(L_ / 32, B_), dim3(256), 0, stream>>>(wp_b, bp_f, x, ot, d_out);
}

// Round 9
// 137.708 us; speedup vs baseline: 1.5702x; 1.0746x over previous
//
#include <hip/hip_runtime.h>
#include <hip/hip_bf16.h>
#include <cstdint>
#include <cstddef>

// B=4, C=128, L=4096, H=4 (hd=32), GROUPS=32, EPS=1e-5
// gn_stats (split stats) -> MFMA qkv v2 (x staged once, 6 out-tiles looped)
// -> MFMA flash attention v10 (this round): REVERT to R3-v4 core (the session-best
//    56.5us config: 128-q blocks, 8 waves = 4 q-tiles x 2 s-halves, 2-buffer LDS,
//    fdot2 l, 32x32 QK/PV MFMA, permlane repack) with two additions:
//      * R6's verified K-swizzle pair (rot = (row>>1)&3): conflicts halved, free.
//      * SPLIT ACCUMULATOR CHAINS: aO -> aO0/aO1 by sb parity (2 indep PV-MFMA
//        chains instead of 4-deep), lsum -> ls0/ls1. Attacks MFMA-accumulate
//        latency, the one dependency class not yet isolated. Summed in epilogue.
// -> MFMA proj v2 (both out-halves per block).
//
// ws layout (bytes):
//   wq_b  bf16 49,152   @ 0
//   wp_b  bf16 16,384   @ 98,304
//   bp_f  f32  128      @ 131,072
//   gpart f32x2 2,048   @ 131,584   [b][g][half] (s, ss)
//   Qt    bf16 2,097,152 @ 8,388,608   [b*H+h][l][32]
//   Kt    bf16 2,097,152 @ 12,582,912  [b*H+h][l][32]
//   Vb    fp16 2,097,152 @ 16,777,216  [b*H+h][32][l]
//   ot    bf16 2,097,152 @ 20,971,520  [b][l][128]

#define B_ 4
#define C_ 128
#define L_ 4096
#define H_ 4
#define HD_ 32
#define NG_ 32
#define CPG_ 4
#define EPS_ 1e-5f
#define QKSCALE_ 0.5050097650430367f  // 32^(-1/4) * sqrt(log2 e)

typedef __attribute__((ext_vector_type(8))) short bf16x8;
typedef __attribute__((ext_vector_type(8))) unsigned short u16x8;
typedef __attribute__((ext_vector_type(4))) float f32x4;
typedef __attribute__((ext_vector_type(16))) float f32x16;
typedef __attribute__((ext_vector_type(2))) _Float16 f16x2;
typedef __attribute__((ext_vector_type(4))) _Float16 f16x4;
typedef __attribute__((ext_vector_type(8))) _Float16 f16x8;
typedef __attribute__((ext_vector_type(2))) unsigned int u32x2;
typedef __attribute__((ext_vector_type(4))) unsigned int u32x4;

#if __has_builtin(__builtin_amdgcn_exp2f)
#define EXP2F(x) __builtin_amdgcn_exp2f(x)
#else
#define EXP2F(x) exp2f(x)
#endif

__device__ __forceinline__ float bu2f(unsigned short u) {
  return __builtin_bit_cast(float, (unsigned int)(((unsigned int)u) << 16));
}
__device__ __forceinline__ unsigned short f2bu(float f) {
  unsigned int u = __builtin_bit_cast(unsigned int, f);
  unsigned int r = (u + 0x7fffu + ((u >> 16) & 1u)) >> 16;  // RNE
  return (unsigned short)r;
}
__device__ __forceinline__ float4 u42f4(ushort4 u) {
  return make_float4(bu2f(u.x), bu2f(u.y), bu2f(u.z), bu2f(u.w));
}
__device__ __forceinline__ unsigned int pkbf(float a, float b) {
  return (unsigned int)f2bu(a) | ((unsigned int)f2bu(b) << 16);
}
__device__ __forceinline__ f16x2 pkhf2(float a, float b) {
#if __has_builtin(__builtin_amdgcn_cvt_pkrtz)
  return __builtin_bit_cast(f16x2, __builtin_amdgcn_cvt_pkrtz(a, b));
#else
  f16x2 r;
  r[0] = (_Float16)a;
  r[1] = (_Float16)b;
  return r;
#endif
}
__device__ __forceinline__ unsigned int pkhf(float a, float b) {
  return __builtin_bit_cast(unsigned int, pkhf2(a, b));
}

// async global->LDS DMA, 16B per lane. LDS dest must be wave-uniform base + lane*16.
__device__ __forceinline__ void gload16(const void* g, void* l) {
  __builtin_amdgcn_global_load_lds(
      (const __attribute__((address_space(1))) unsigned int*)g,
      (__attribute__((address_space(3))) unsigned int*)l, 16, 0, 0);
}

// fp32-vs-bf16 detection via wave-0 ballot — proven R9.
__device__ __forceinline__ bool detect_fast(const ushort* x) {
  __shared__ int flag_s;
  int t = threadIdx.x;
  if (t < 64) {
    int e = (x[t] >> 7) & 0xFF;
    unsigned long long m = __ballot((e < 64) || (e > 192));
    if (t == 0) flag_s = (__popcll(m) > 4) ? 1 : 0;
  }
  __syncthreads();
  return flag_s != 0;
}

__device__ __forceinline__ float4 ldx4(const void* x, size_t idx, bool f32) {
  if (f32) return *((const float4*)x + (idx >> 2));
  ushort4 u = *((const ushort4*)x + (idx >> 2));
  return u42f4(u);
}

// ---------------------------------------------------------------- GN stats + weight cvt
__global__ __launch_bounds__(256) void gn_stats(const void* __restrict__ x,
                                                const void* __restrict__ wq,
                                                const void* __restrict__ wp,
                                                const void* __restrict__ bp,
                                                ushort* __restrict__ wq_b,
                                                ushort* __restrict__ wp_b,
                                                float* __restrict__ bp_f,
                                                float2* __restrict__ gpart) {
  bool f32 = detect_fast((const ushort*)x);
  int blk = blockIdx.x;
  int t = threadIdx.x;

  if (blk >= 256) {
    int i0 = ((blk - 256) * 256 + t) * 8;
#pragma unroll
    for (int k = 0; k < 8; ++k) {
      int i = i0 + k;
      if (i >= 65664) break;
      if (i < 49152) {
        wq_b[i] = f32 ? f2bu(((const float*)wq)[i]) : ((const ushort*)wq)[i];
      } else if (i < 65536) {
        int off = i - 49152;
        wp_b[off] = f32 ? f2bu(((const float*)wp)[off]) : ((const ushort*)wp)[off];
      } else {
        int off = i - 65536;
        bp_f[off] = f32 ? ((const float*)bp)[off] : bu2f(((const ushort*)bp)[off]);
      }
    }
    return;
  }

  int b = blk >> 6, rem = blk & 63;
  int g = rem >> 1, half = rem & 1;
  size_t base = ((size_t)b * C_ + (size_t)g * CPG_) * L_ + (size_t)half * 2048;

  float s = 0.f, ss = 0.f;
#pragma unroll
  for (int cc = 0; cc < 4; ++cc) {
#pragma unroll
    for (int i = 0; i < 2; ++i) {
      size_t e = base + (size_t)cc * L_ + i * 1024 + t * 4;
      float4 f = ldx4(x, e, f32);
      s += f.x + f.y + f.z + f.w;
      ss += f.x * f.x + f.y * f.y + f.z * f.z + f.w * f.w;
    }
  }
#pragma unroll
  for (int m = 32; m >= 1; m >>= 1) {
    s += __shfl_xor(s, m, 64);
    ss += __shfl_xor(ss, m, 64);
  }
  __shared__ float red[4][2];
  int wv = t >> 6;
  if ((t & 63) == 0) { red[wv][0] = s; red[wv][1] = ss; }
  __syncthreads();
  if (t == 0) {
    float ts = red[0][0] + red[1][0] + red[2][0] + red[3][0];
    float tss = red[0][1] + red[1][1] + red[2][1] + red[3][1];
    gpart[(b * 32 + g) * 2 + half] = make_float2(ts, tss);
  }
}

// ---------------------------------------------------------------- QKV GEMM v2
__global__ __launch_bounds__(256) void qkv_kernel(const ushort* __restrict__ wq_b,
                                                  const void* __restrict__ x,
                                                  const float2* __restrict__ gpart,
                                                  const void* __restrict__ gm,
                                                  const void* __restrict__ bt,
                                                  ushort* __restrict__ Qt,
                                                  ushort* __restrict__ Kt,
                                                  ushort* __restrict__ Vb) {
  bool f32 = detect_fast((const ushort*)x);
  __shared__ alignas(16) ushort Hs[32][136];
  __shared__ alignas(16) float Ls[32][69];
  __shared__ float2 abs_s[128];

  int lx = blockIdx.x, b = blockIdx.y;
  int t = threadIdx.x;
  int w = t >> 6, lane = t & 63, l16 = lane & 15, q = lane >> 4, q8 = q * 8;

  if (t < 64) {
#pragma unroll
    for (int k = 0; k < 2; ++k) {
      int c = 2 * t + k;
      int g = c >> 2;
      float2 p0 = gpart[(b * 32 + g) * 2];
      float2 p1 = gpart[(b * 32 + g) * 2 + 1];
      float mu = (p0.x + p1.x) * (1.0f / 16384.0f);
      float var = (p0.y + p1.y) * (1.0f / 16384.0f) - mu * mu;
      float rs = rsqrtf(var + EPS_);
      float ga = f32 ? ((const float*)gm)[c] : bu2f(((const ushort*)gm)[c]);
      float be = f32 ? ((const float*)bt)[c] : bu2f(((const ushort*)bt)[c]);
      abs_s[c] = make_float2(ga * rs, be - mu * ga * rs);
    }
  }
  __syncthreads();

  {
    int u = t & 63, lh = w * 8;
    int c0 = 2 * u;
    float2 ab0 = abs_s[c0];
    float2 ab1 = abs_s[c0 + 1];
    size_t xo = ((size_t)b * C_ + c0) * L_ + (size_t)lx * 32 + lh;
#pragma unroll
    for (int j = 0; j < 2; ++j) {
      float4 f0 = ldx4(x, xo + j * 4, f32);
      float4 f1 = ldx4(x, xo + L_ + j * 4, f32);
      float n0[4] = {f0.x * ab0.x + ab0.y, f0.y * ab0.x + ab0.y,
                     f0.z * ab0.x + ab0.y, f0.w * ab0.x + ab0.y};
      float n1[4] = {f1.x * ab1.x + ab1.y, f1.y * ab1.x + ab1.y,
                     f1.z * ab1.x + ab1.y, f1.w * ab1.x + ab1.y};
#pragma unroll
      for (int k = 0; k < 4; ++k)
        *(unsigned int*)&Hs[lh + j * 4 + k][c0] = pkbf(n0[k], n1[k]);
    }
  }
  __syncthreads();

  for (int oy = 0; oy < 6; ++oy) {
    const ushort* wg = wq_b + (size_t)(oy * 64 + w * 16 + l16) * C_;

    f32x4 acc[2] = {{0.f, 0.f, 0.f, 0.f}, {0.f, 0.f, 0.f, 0.f}};
#pragma unroll
    for (int kc = 0; kc < 4; ++kc) {
      bf16x8 aw = *(const bf16x8*)(wg + kc * 32 + q8);
#pragma unroll
      for (int nb = 0; nb < 2; ++nb) {
        bf16x8 bh = *(const bf16x8*)&Hs[nb * 16 + l16][kc * 32 + q8];
        acc[nb] = __builtin_amdgcn_mfma_f32_16x16x32_bf16(aw, bh, acc[nb], 0, 0, 0);
      }
    }
    __syncthreads();
#pragma unroll
    for (int nb = 0; nb < 2; ++nb)
#pragma unroll
      for (int r = 0; r < 4; ++r)
        Ls[nb * 16 + l16][w * 16 + 4 * q + r] = acc[nb][r];
    __syncthreads();

#pragma unroll
    for (int hhalf = 0; hhalf < 2; ++hhalf) {
      int hh = oy * 2 + hhalf;
      int type = hh % 3, head = hh / 3;
      size_t bh = (size_t)b * H_ + head;
      if (type == 2) {
        int c_loc = t >> 3, l4 = (t & 7) * 4;
        float v[4];
#pragma unroll
        for (int jj = 0; jj < 4; ++jj) v[jj] = Ls[l4 + jj][hhalf * 32 + c_loc];
        uint2 u;
        u.x = pkhf(v[0], v[1]);
        u.y = pkhf(v[2], v[3]);
        *(uint2*)(Vb + (bh * 32 + c_loc) * L_ + (size_t)lx * 32 + l4) = u;
      } else {
        ushort* dst = type ? Kt : Qt;
        int l = t >> 3, seg = (t & 7) * 4;
        const float* src = &Ls[l][hhalf * 32 + seg];
        uint2 u;
        u.x = pkbf(src[0] * QKSCALE_, src[1] * QKSCALE_);
        u.y = pkbf(src[2] * QKSCALE_, src[3] * QKSCALE_);
        *(uint2*)(dst + ((bh * L_) + lx * 32 + l) * 32 + seg) = u;
      }
    }
  }
}

// ---------------------------------------------------------------- MFMA flash attention v10
// R3-v4 core: 128-q blocks, 8 waves = 4 q-tiles (qt=w&3) x 2 s-halves (sh=w>>2),
// 128 s/iter, 2-buffer LDS + __syncthreads. K swizzle: phys chunk = (c + (row>>1))&3
// (R6 fix, conflict-free-er). V swizzle: chunk = (c&8)|((c&7)^(row&7)).
// Split accumulator chains: aO0/aO1 and ls0/ls1 by sb parity (halves the per-iter
// dependent MFMA-accumulate chain), summed in the epilogue.
__global__ __launch_bounds__(512) void attn_kernel(const ushort* __restrict__ Qt,
                                                   const ushort* __restrict__ Kt,
                                                   const ushort* __restrict__ Vb,
                                                   ushort* __restrict__ ot) {
  // K bufs: [0,8192),[8192,16384) ; V bufs: [16384,24576),[24576,32768)
  // epilogue overlay: Osh [8][32][33] f32 = 33792B @0 ; Lp [4][128] f32 @33792 (2048B)
  __shared__ alignas(16) char smem[35840];

  int t = threadIdx.x;
  int w = t >> 6, lane = t & 63, l31 = lane & 31, hi = lane >> 5;
  int qt = w & 3, sh = w >> 2;
  int tq0 = blockIdx.x * 128;
  int bh = blockIdx.y;
  int b = bh >> 2, head = bh & 3;
  const ushort* Qg = Qt + ((size_t)bh * L_ + tq0) * 32;
  const ushort* Kg = Kt + (size_t)bh * L_ * 32;
  const ushort* Vg = Vb + (size_t)bh * 32 * L_;

  // staging sources (pre-swizzled so linear DMA dest yields swizzled LDS)
  int rd = t >> 2, pd = t & 3;
  int kcsem = (pd - (rd >> 1)) & 3;
  const ushort* ksrc = Kg + (size_t)rd * 32 + kcsem * 8;
  int vr = t >> 4, vp = t & 15;
  int vcsem = (vp & 8) | ((vp & 7) ^ (vr & 7));
  const ushort* vsrc = Vg + (size_t)vr * L_ + vcsem * 8;

  char* kb0 = smem;
  char* kb1 = smem + 8192;
  char* vb0 = smem + 16384;
  char* vb1 = smem + 24576;

  // Q fragments (B operand): lane holds Q[q=qt*32+l31][k = 8*hi + j] (+16 for 2nd K-half)
  const ushort* qbase = Qg + (size_t)(qt * 32 + l31) * 32;
  bf16x8 qB0 = *(const bf16x8*)(qbase + 8 * hi);
  bf16x8 qB1 = *(const bf16x8*)(qbase + 16 + 8 * hi);

  const f16x2 one2 = {(_Float16)1.0f, (_Float16)1.0f};
  const f32x16 zz = {0.f};

  // prologue: DMA tile 0 into buf A
  gload16(ksrc, kb0 + (size_t)t * 16);
  gload16(vsrc, vb0 + (size_t)t * 16);
  ksrc += 4096;
  vsrc += 128;
  __syncthreads();

  f32x16 aO0 = {0.f}, aO1 = {0.f};
  float ls0 = 0.f, ls1 = 0.f;
  int rot = (l31 >> 1) & 3;

  int flip = 0;
  for (int it = 0; it < 32; ++it) {
    if (it < 31) {
      gload16(ksrc, (flip ? kb0 : kb1) + (size_t)t * 16);
      gload16(vsrc, (flip ? vb0 : vb1) + (size_t)t * 16);
      ksrc += 4096;
      vsrc += 128;
    }
    const ushort* kc = (const ushort*)(flip ? kb1 : kb0);
    const ushort* vc = (const ushort*)(flip ? vb1 : vb0);

#pragma unroll
    for (int st = 0; st < 2; ++st) {
      int s0 = 64 * sh + 32 * st;
      const ushort* krow = kc + (size_t)(s0 + l31) * 32;
      bf16x8 aK0 = *(const bf16x8*)(krow + ((hi + rot) & 3) * 8);
      bf16x8 aK1 = *(const bf16x8*)(krow + ((2 + hi + rot) & 3) * 8);
      f32x16 sf;
      __builtin_amdgcn_s_setprio(1);
      sf = __builtin_amdgcn_mfma_f32_32x32x16_bf16(aK0, qB0, zz, 0, 0, 0);
      sf = __builtin_amdgcn_mfma_f32_32x32x16_bf16(aK1, qB1, sf, 0, 0, 0);
      __builtin_amdgcn_s_setprio(0);

#pragma unroll
      for (int sb = 0; sb < 2; ++sb) {
        int sblk = 4 * sh + 2 * st + sb;
        // V fragment (A operand): V[c=l31][s = sblk*16 + 8*hi + j]
        int kci = 2 * sblk + hi;
        int vpos = (kci & 8) | ((kci & 7) ^ (l31 & 7));
        f16x8 vf = *(const f16x8*)(vc + (size_t)l31 * 128 + vpos * 8);

        float p0 = EXP2F(sf[8 * sb + 0]);
        float p1 = EXP2F(sf[8 * sb + 1]);
        float p2 = EXP2F(sf[8 * sb + 2]);
        float p3 = EXP2F(sf[8 * sb + 3]);
        float p4 = EXP2F(sf[8 * sb + 4]);
        float p5 = EXP2F(sf[8 * sb + 5]);
        float p6 = EXP2F(sf[8 * sb + 6]);
        float p7 = EXP2F(sf[8 * sb + 7]);
        f16x2 cA0 = pkhf2(p0, p1), cA1 = pkhf2(p2, p3);
        f16x2 cB0 = pkhf2(p4, p5), cB1 = pkhf2(p6, p7);
        if (sb == 0) {
          ls0 = __builtin_amdgcn_fdot2(cA0, one2, ls0, false);
          ls0 = __builtin_amdgcn_fdot2(cA1, one2, ls0, false);
          ls0 = __builtin_amdgcn_fdot2(cB0, one2, ls0, false);
          ls0 = __builtin_amdgcn_fdot2(cB1, one2, ls0, false);
        } else {
          ls1 = __builtin_amdgcn_fdot2(cA0, one2, ls1, false);
          ls1 = __builtin_amdgcn_fdot2(cA1, one2, ls1, false);
          ls1 = __builtin_amdgcn_fdot2(cB0, one2, ls1, false);
          ls1 = __builtin_amdgcn_fdot2(cB1, one2, ls1, false);
        }

        // B-fragment repack: (w0,w2) = swap(cA0, cB0); (w1,w3) = swap(cA1, cB1)
        u32x2 r0 = __builtin_amdgcn_permlane32_swap(
            __builtin_bit_cast(unsigned int, cA0),
            __builtin_bit_cast(unsigned int, cB0), false, false);
        u32x2 r1 = __builtin_amdgcn_permlane32_swap(
            __builtin_bit_cast(unsigned int, cA1),
            __builtin_bit_cast(unsigned int, cB1), false, false);
        u32x4 pw = {r0.x, r1.x, r0.y, r1.y};
        f16x8 pf = __builtin_bit_cast(f16x8, pw);

        __builtin_amdgcn_s_setprio(1);
        if (sb == 0)
          aO0 = __builtin_amdgcn_mfma_f32_32x32x16_f16(vf, pf, aO0, 0, 0, 0);
        else
          aO1 = __builtin_amdgcn_mfma_f32_32x32x16_f16(vf, pf, aO1, 0, 0, 0);
        __builtin_amdgcn_s_setprio(0);
      }
    }
    __syncthreads();
    flip ^= 1;
  }

  // ---- epilogue: write partials (padded rows: bank = (l31 + word) % 32)
  float* Osh = (float*)smem;                // [slot=sh*4+qt][q=32][c=33pad]
  float* Lp = (float*)(smem + 33792);       // [sh*2+hi][128]
  {
    float* ob = Osh + (size_t)(sh * 4 + qt) * (32 * 33) + (size_t)l31 * 33;
#pragma unroll
    for (int reg = 0; reg < 16; ++reg) {
      int R = (reg & 3) + 8 * (reg >> 2) + 4 * hi;
      ob[R] = aO0[reg] + aO1[reg];
    }
    Lp[(sh * 2 + hi) * 128 + qt * 32 + l31] = ls0 + ls1;
  }
  __syncthreads();

  // combine s-halves + hi-halves, normalize, pack bf16, coalesced store
  {
    int qloc = t >> 2, c0 = (t & 3) * 8;
    int qt2 = qloc >> 5, q31 = qloc & 31;
    float lt = Lp[qloc] + Lp[128 + qloc] + Lp[256 + qloc] + Lp[384 + qloc];
    float inv = 1.0f / lt;
    const float* o0 = Osh + (size_t)qt2 * (32 * 33) + (size_t)q31 * 33 + c0;
    const float* o1 = o0 + 4 * (32 * 33);
    float o[8];
#pragma unroll
    for (int jj = 0; jj < 8; ++jj) o[jj] = (o0[jj] + o1[jj]) * inv;
    uint4 u;
    u.x = pkbf(o[0], o[1]);
    u.y = pkbf(o[2], o[3]);
    u.z = pkbf(o[4], o[5]);
    u.w = pkbf(o[6], o[7]);
    *(uint4*)(ot + ((size_t)b * L_ + tq0 + qloc) * C_ + head * 32 + c0) = u;
  }
}

// ---------------------------------------------------------------- Proj v2 + bias + residual
__global__ __launch_bounds__(256) void proj_kernel(const ushort* __restrict__ wp_b,
                                                   const float* __restrict__ bias,
                                                   const void* __restrict__ x,
                                                   const ushort* __restrict__ ot,
                                                   void* __restrict__ out) {
  bool f32 = detect_fast((const ushort*)x);
  __shared__ alignas(16) float Ls[128][33];

  int lx = blockIdx.x, b = blockIdx.y;
  int t = threadIdx.x;
  int w = t >> 6, lane = t & 63, l16 = lane & 15, q = lane >> 4, q8 = q * 8;

  const ushort* wg0 = wp_b + (size_t)(w * 16 + l16) * C_;
  const ushort* wg1 = wp_b + (size_t)(64 + w * 16 + l16) * C_;
  const ushort* og = ot + ((size_t)b * L_ + (size_t)lx * 32) * C_;

  f32x4 acc[2][2] = {{{0.f, 0.f, 0.f, 0.f}, {0.f, 0.f, 0.f, 0.f}},
                     {{0.f, 0.f, 0.f, 0.f}, {0.f, 0.f, 0.f, 0.f}}};
#pragma unroll
  for (int kc = 0; kc < 4; ++kc) {
    bf16x8 aw0 = *(const bf16x8*)(wg0 + kc * 32 + q8);
    bf16x8 aw1 = *(const bf16x8*)(wg1 + kc * 32 + q8);
#pragma unroll
    for (int nb = 0; nb < 2; ++nb) {
      bf16x8 bo = *(const bf16x8*)(og + (size_t)(nb * 16 + l16) * C_ + kc * 32 + q8);
      acc[0][nb] = __builtin_amdgcn_mfma_f32_16x16x32_bf16(aw0, bo, acc[0][nb], 0, 0, 0);
      acc[1][nb] = __builtin_amdgcn_mfma_f32_16x16x32_bf16(aw1, bo, acc[1][nb], 0, 0, 0);
    }
  }
#pragma unroll
  for (int oy = 0; oy < 2; ++oy)
#pragma unroll
    for (int nb = 0; nb < 2; ++nb)
#pragma unroll
      for (int r = 0; r < 4; ++r)
        Ls[oy * 64 + w * 16 + 4 * q + r][nb * 16 + l16] = acc[oy][nb][r];
  __syncthreads();

  {
    int o_loc = t >> 1, ls0 = (t & 1) * 16;
    float bv = bias[o_loc];
    size_t off = ((size_t)b * C_ + o_loc) * L_ + (size_t)lx * 32 + ls0;
#pragma unroll
    for (int jj = 0; jj < 4; ++jj) {
      float4 xf = ldx4(x, off + jj * 4, f32);
      const float* sp = &Ls[o_loc][ls0 + jj * 4];
      float4 r = make_float4(sp[0] + bv + xf.x, sp[1] + bv + xf.y,
                             sp[2] + bv + xf.z, sp[3] + bv + xf.w);
      if (f32) {
        *(float4*)((float*)out + off + jj * 4) = r;
      } else {
        *(ushort4*)((ushort*)out + off + jj * 4) =
            make_ushort4(f2bu(r.x), f2bu(r.y), f2bu(r.z), f2bu(r.w));
      }
    }
  }
}

// ---------------------------------------------------------------- launch
extern "C" void kernel_launch(void* const* d_in, const int* in_sizes, int n_in,
                              void* d_out, int out_size, void* d_ws, size_t ws_size,
                              hipStream_t stream) {
  const void* x      = d_in[0];
  const void* w_qkv  = d_in[1];
  const void* w_proj = d_in[2];
  const void* b_proj = d_in[3];
  const void* gamma  = d_in[4];
  const void* beta   = d_in[5];

  char* wsb = (char*)d_ws;
  ushort* wq_b  = (ushort*)(wsb + 0);
  ushort* wp_b  = (ushort*)(wsb + 98304);
  float*  bp_f  = (float*)(wsb + 131072);
  float2* gpart = (float2*)(wsb + 131584);
  ushort* Qt    = (ushort*)(wsb + 8388608);
  ushort* Kt    = (ushort*)(wsb + 12582912);
  ushort* Vb    = (ushort*)(wsb + 16777216);  // fp16
  ushort* ot    = (ushort*)(wsb + 20971520);

  gn_stats<<<dim3(289), dim3(256), 0, stream>>>(x, w_qkv, w_proj, b_proj,
                                                wq_b, wp_b, bp_f, gpart);
  qkv_kernel<<<dim3(L_ / 32, B_), dim3(256), 0, stream>>>(wq_b, x, gpart, gamma, beta,
                                                          Qt, Kt, Vb);
  attn_kernel<<<dim3(L_ / 128, B_ * H_), dim3(512), 0, stream>>>(Qt, Kt, Vb, ot);
  proj_kernel<<<dim3(L_ / 32, B_), dim3(256), 0, stream>>>(wp_b, bp_f, x, ot, d_out);
}